// Round 4
// baseline (630.949 us; speedup 1.0000x reference)
//
#include <hip/hip_runtime.h>

#define NNODES 50000
#define NEDGES 500000
#define NBINS  (NNODES * 4)
#define NSCANB 196   // ceil(NBINS / 1024)
#define MPAD   50176 // 784*64

// wf fp32 arena offsets (in floats). SSC is padded to a multiple of 4 so the
// per-nt score vectors (cell*64 + nt*16 + q*4) are 16B-aligned floatx4 loads.
#define WF_W1    0
#define WF_B1    4096
#define WF_W2    4160
#define WF_B2    8256
#define WF_W3    8320
#define WF_B3    8384
#define WF_SSC   8388
#define WF_STC   9412
#define WF_BIAS  10436
#define WF_GAMMA 10692
#define WF_BETA  10948
#define WF_TOT   11204

typedef __attribute__((ext_vector_type(8))) short short8;
typedef __attribute__((ext_vector_type(4))) short short4v;
typedef __attribute__((ext_vector_type(4))) float floatx4;
typedef __attribute__((ext_vector_type(4))) unsigned int uint4v;

__device__ __forceinline__ float bf2f(unsigned short u) {
    return __uint_as_float(((unsigned)u) << 16);
}
__device__ __forceinline__ unsigned f2bf(float f) {
    unsigned u = __float_as_uint(f);
    u += 0x7fffu + ((u >> 16) & 1u);
    return u >> 16;
}
__device__ __forceinline__ int clampi(int v, int hi) { return v < 0 ? 0 : (v > hi ? hi : v); }

__device__ __forceinline__ short8 pack_bf16(const float* p) {
    short8 r;
#pragma unroll
    for (int j = 0; j < 8; j++) r[j] = (short)f2bf(p[j]);
    return r;
}

// ---------------------------------------------------------------------------
// dtype probe: flag=1 means inputs are fp32
// ---------------------------------------------------------------------------
__global__ __launch_bounds__(256) void probe_k(const unsigned short* __restrict__ xs,
                                               unsigned* __restrict__ flag) {
    __shared__ unsigned cnt;
    if (threadIdx.x == 0) cnt = 0;
    __syncthreads();
    unsigned local = 0;
    for (int i = threadIdx.x; i < 8192; i += 256) {
        float v = bf2f(xs[i]);
        if (!(fabsf(v) < 1e10f)) local++;
    }
    atomicAdd(&cnt, local);
    __syncthreads();
    if (threadIdx.x == 0) *flag = (cnt > 256u) ? 1u : 0u;
}

// ---------------------------------------------------------------------------
// polymorphic small-param conversion into fp32 arena
// ---------------------------------------------------------------------------
__device__ __forceinline__ float ldf(const void* p, int i, bool f32) {
    return f32 ? ((const float*)p)[i] : bf2f(((const unsigned short*)p)[i]);
}

__global__ __launch_bounds__(1024) void wconv_k(const void* W1, const void* b1,
                                                const void* W2, const void* b2,
                                                const void* W3, const void* b3,
                                                const void* ssc, const void* stc,
                                                const void* bias, const void* gamma,
                                                const void* beta,
                                                const unsigned* __restrict__ flag,
                                                float* __restrict__ wf) {
    bool f32 = (*flag != 0u);
    for (int i = threadIdx.x; i < WF_TOT; i += 1024) {
        float v;
        if (i < WF_B1)          v = ldf(W1, i - WF_W1, f32);
        else if (i < WF_W2)     v = ldf(b1, i - WF_B1, f32);
        else if (i < WF_B2)     v = ldf(W2, i - WF_W2, f32);
        else if (i < WF_W3)     v = ldf(b2, i - WF_B2, f32);
        else if (i < WF_B3)     v = ldf(W3, i - WF_W3, f32);
        else if (i < WF_SSC) {  // b3 (size 1) + 3 floats of alignment pad
            int j = i - WF_B3;
            v = (j < 1) ? ldf(b3, j, f32) : 0.f;
        }
        else if (i < WF_STC)    v = ldf(ssc, i - WF_SSC, f32);
        else if (i < WF_BIAS)   v = ldf(stc, i - WF_STC, f32);
        else if (i < WF_GAMMA)  v = ldf(bias, i - WF_BIAS, f32);
        else if (i < WF_BETA)   v = ldf(gamma, i - WF_GAMMA, f32);
        else                    v = ldf(beta, i - WF_BETA, f32);
        wf[i] = v;
    }
}

// ---------------------------------------------------------------------------
// bulk matrix conversion (fp32|bf16 -> bf16), zero-padded to npad elems
// ---------------------------------------------------------------------------
__global__ __launch_bounds__(256) void convbf_k(const void* __restrict__ src,
                                                unsigned short* __restrict__ dst,
                                                int nelem, int npad,
                                                const unsigned* __restrict__ flag) {
    int i8 = (blockIdx.x * 256 + threadIdx.x) * 8;
    if (i8 >= npad) return;
    short8 o;
    if (i8 < nelem) {
        if (*flag) {
            const float* pf = (const float*)src + i8;
            floatx4 a = *(const floatx4*)pf;
            floatx4 b = *(const floatx4*)(pf + 4);
            o[0] = (short)f2bf(a[0]); o[1] = (short)f2bf(a[1]);
            o[2] = (short)f2bf(a[2]); o[3] = (short)f2bf(a[3]);
            o[4] = (short)f2bf(b[0]); o[5] = (short)f2bf(b[1]);
            o[6] = (short)f2bf(b[2]); o[7] = (short)f2bf(b[3]);
        } else {
            o = *(const short8*)((const unsigned short*)src + i8);
        }
    } else {
#pragma unroll
        for (int j = 0; j < 8; j++) o[j] = 0;
    }
    *(short8*)(dst + i8) = o;
}

// ---------------------------------------------------------------------------
// fused one-pass GEMM (R1 base: reg A-stripe, cg-split over gridDim.y) with
// SWAPPED MFMA operands: mfma(B_frag, A_frag) -> lane l15 = x-row, (q,rg) =
// weight-col. Each lane then owns 4 CONTIGUOUS output cols -> proj stores are
// short4v (8B/lane), skip stores floatx4 (16B/lane, full 64B sectors).
// Stores use nontemporal hints so the 165MB write stream stops evicting A/B
// from L2 (theory: all prior variants were latency-bound on B/A loads because
// the write stream thrashed the 4MB/XCD L2).
// ---------------------------------------------------------------------------
__global__ __launch_bounds__(64) void gemm_fused_k(const unsigned short* __restrict__ A,
                                                   const unsigned short* __restrict__ Bp,
                                                   const unsigned short* __restrict__ Bs,
                                                   unsigned short* __restrict__ proj,
                                                   unsigned short* __restrict__ out16,
                                                   float* __restrict__ out32,
                                                   const float* __restrict__ wf,
                                                   float* __restrict__ s_src,
                                                   float* __restrict__ s_trg,
                                                   const unsigned* __restrict__ flag) {
    const bool cf32 = (*flag != 0u);
    const int lane = threadIdx.x & 63;
    const int l15 = lane & 15, q = lane >> 4;
    const int m0 = blockIdx.x * 64;
    const int cg0 = blockIdx.y * 4;   // 0,4,8,12 = proj groups; 16 = skip groups

    // A-stripe: 64 rows x 256 K in registers (128 VGPRs)
    short8 af[4][8];
#pragma unroll
    for (int mt = 0; mt < 4; mt++)
#pragma unroll
        for (int ks = 0; ks < 8; ks++)
            af[mt][ks] = *(const short8*)(A + (size_t)(m0 + mt * 16 + l15) * 256 + ks * 32 + q * 8);

    if (cg0 < 16) {
        // ---- proj columns (4 of 16) ----
#pragma unroll 1
        for (int cgi = 0; cgi < 4; cgi++) {
            const int cg = cg0 + cgi;
            floatx4 acc[4][4];
#pragma unroll
            for (int i = 0; i < 4; i++)
#pragma unroll
                for (int j = 0; j < 4; j++) acc[i][j] = (floatx4){0.f, 0.f, 0.f, 0.f};
#pragma unroll
            for (int ks = 0; ks < 8; ks++) {
                short8 bfr[4];
#pragma unroll
                for (int nt = 0; nt < 4; nt++)
                    bfr[nt] = *(const short8*)(Bp + (size_t)(cg * 64 + nt * 16 + l15) * 256 + ks * 32 + q * 8);
#pragma unroll
                for (int mt = 0; mt < 4; mt++)
#pragma unroll
                    for (int nt = 0; nt < 4; nt++)
                        acc[mt][nt] = __builtin_amdgcn_mfma_f32_16x16x32_bf16(bfr[nt], af[mt][ks],
                                                                             acc[mt][nt], 0, 0, 0);
            }
            const int h = cg >> 2, r = cg & 3;
            const int colbase = (r * 4 + h) * 64;   // (r,h,f) layout
            const int cell = h * 4 + r;             // s_src/s_trg cell index
            floatx4 sa4[4], sb4[4];
#pragma unroll
            for (int nt = 0; nt < 4; nt++) {
                sa4[nt] = *(const floatx4*)(wf + WF_SSC + cell * 64 + nt * 16 + q * 4);
                sb4[nt] = *(const floatx4*)(wf + WF_STC + cell * 64 + nt * 16 + q * 4);
            }
#pragma unroll
            for (int mt = 0; mt < 4; mt++) {
                const int row = m0 + mt * 16 + l15;
                float pa = 0.f, pb = 0.f;
#pragma unroll
                for (int nt = 0; nt < 4; nt++) {
                    short4v sv;
#pragma unroll
                    for (int rg = 0; rg < 4; rg++) {
                        float v = acc[mt][nt][rg];
                        unsigned short vb = (unsigned short)f2bf(v);
                        sv[rg] = (short)vb;
                        float vr = bf2f(vb);   // match prior bf16-rounded score path
                        pa = fmaf(vr, sa4[nt][rg], pa);
                        pb = fmaf(vr, sb4[nt][rg], pb);
                    }
                    if (row < NNODES)
                        __builtin_nontemporal_store(sv,
                            (short4v*)(proj + (size_t)row * 1024 + colbase + nt * 16 + q * 4));
                }
                pa += __shfl_xor(pa, 16);
                pa += __shfl_xor(pa, 32);
                pb += __shfl_xor(pb, 16);
                pb += __shfl_xor(pb, 32);
                if (q == 0 && row < NNODES) {
                    s_src[row * 16 + cell] = pa;
                    s_trg[row * 16 + cell] = pb;
                }
            }
        }
    } else {
        // ---- skip columns (all 4) ----
#pragma unroll 1
        for (int cg = 0; cg < 4; cg++) {
            floatx4 acc[4][4];
#pragma unroll
            for (int i = 0; i < 4; i++)
#pragma unroll
                for (int j = 0; j < 4; j++) acc[i][j] = (floatx4){0.f, 0.f, 0.f, 0.f};
#pragma unroll
            for (int ks = 0; ks < 8; ks++) {
                short8 bfr[4];
#pragma unroll
                for (int nt = 0; nt < 4; nt++)
                    bfr[nt] = *(const short8*)(Bs + (size_t)(cg * 64 + nt * 16 + l15) * 256 + ks * 32 + q * 8);
#pragma unroll
                for (int mt = 0; mt < 4; mt++)
#pragma unroll
                    for (int nt = 0; nt < 4; nt++)
                        acc[mt][nt] = __builtin_amdgcn_mfma_f32_16x16x32_bf16(bfr[nt], af[mt][ks],
                                                                             acc[mt][nt], 0, 0, 0);
            }
#pragma unroll
            for (int mt = 0; mt < 4; mt++) {
                const int row = m0 + mt * 16 + l15;
                if (row >= NNODES) continue;
#pragma unroll
                for (int nt = 0; nt < 4; nt++) {
                    if (cf32) {
                        floatx4 o = acc[mt][nt];
                        __builtin_nontemporal_store(o,
                            (floatx4*)(out32 + (size_t)row * 256 + cg * 64 + nt * 16 + q * 4));
                    } else {
                        short4v sv;
#pragma unroll
                        for (int rg = 0; rg < 4; rg++)
                            sv[rg] = (short)f2bf(acc[mt][nt][rg]);
                        __builtin_nontemporal_store(sv,
                            (short4v*)(out16 + (size_t)row * 256 + cg * 64 + nt * 16 + q * 4));
                    }
                }
            }
        }
    }
}

// ---------------------------------------------------------------------------
// CSR build: count -> hierarchical scan -> fill
// ---------------------------------------------------------------------------
__global__ __launch_bounds__(256) void count_k(const int* __restrict__ trg,
                                               const int* __restrict__ rel,
                                               unsigned* __restrict__ counts, int E) {
    int e = blockIdx.x * 256 + threadIdx.x;
    if (e >= E) return;
    int g = clampi(trg[e], NNODES - 1);
    int r = clampi(rel[e], 3);
    atomicAdd(&counts[g * 4 + r], 1u);
}

__global__ __launch_bounds__(256) void scan1_k(const unsigned* __restrict__ counts,
                                               unsigned* __restrict__ offsets,
                                               unsigned* __restrict__ bsum) {
    __shared__ unsigned ts[256];
    int t = threadIdx.x;
    int base = blockIdx.x * 1024 + t * 4;
    uint4v c = {0u, 0u, 0u, 0u};
    if (base + 3 < NBINS) c = *(const uint4v*)(counts + base);
    else {
#pragma unroll
        for (int j = 0; j < 4; j++) c[j] = (base + j < NBINS) ? counts[base + j] : 0u;
    }
    ts[t] = c[0] + c[1] + c[2] + c[3];
    __syncthreads();
    for (int off = 1; off < 256; off <<= 1) {
        unsigned v = (t >= off) ? ts[t - off] : 0u;
        __syncthreads();
        ts[t] += v;
        __syncthreads();
    }
    unsigned pre = (t == 0) ? 0u : ts[t - 1];
    uint4v o;
    o[0] = pre;
    o[1] = pre + c[0];
    o[2] = pre + c[0] + c[1];
    o[3] = pre + c[0] + c[1] + c[2];
    if (base + 3 < NBINS) *(uint4v*)(offsets + base) = o;
    else {
#pragma unroll
        for (int j = 0; j < 4; j++) if (base + j < NBINS) offsets[base + j] = o[j];
    }
    if (t == 255) bsum[blockIdx.x] = ts[255];
}

__global__ __launch_bounds__(256) void scan2_k(unsigned* __restrict__ bsum,
                                               unsigned* __restrict__ offsets) {
    __shared__ unsigned ts[256];
    int t = threadIdx.x;
    unsigned v = (t < NSCANB) ? bsum[t] : 0u;
    ts[t] = v;
    __syncthreads();
    for (int off = 1; off < 256; off <<= 1) {
        unsigned u = (t >= off) ? ts[t - off] : 0u;
        __syncthreads();
        ts[t] += u;
        __syncthreads();
    }
    if (t < NSCANB) bsum[t] = (t == 0) ? 0u : ts[t - 1];
    if (t == 255) offsets[NBINS] = ts[255];
}

__global__ __launch_bounds__(256) void scan3_k(unsigned* __restrict__ offsets,
                                               unsigned* __restrict__ cursor,
                                               const unsigned* __restrict__ bsum) {
    int t = threadIdx.x;
    unsigned base = bsum[blockIdx.x];
    int idx = blockIdx.x * 1024 + t * 4;
    if (idx + 3 < NBINS) {
        uint4v o = *(const uint4v*)(offsets + idx);
        o[0] += base; o[1] += base; o[2] += base; o[3] += base;
        *(uint4v*)(offsets + idx) = o;
        *(uint4v*)(cursor + idx) = o;
    } else {
#pragma unroll
        for (int j = 0; j < 4; j++)
            if (idx + j < NBINS) {
                unsigned v = offsets[idx + j] + base;
                offsets[idx + j] = v;
                cursor[idx + j] = v;
            }
    }
}

__global__ __launch_bounds__(256) void fill_k(const int* __restrict__ src,
                                              const int* __restrict__ trg,
                                              const int* __restrict__ rel,
                                              const float* __restrict__ s_src,
                                              const float* __restrict__ s_trg,
                                              unsigned* __restrict__ cursor,
                                              unsigned* __restrict__ esrc,
                                              floatx4* __restrict__ eexp, int E) {
    int e = blockIdx.x * 256 + threadIdx.x;
    if (e >= E) return;
    int s = clampi(src[e], NNODES - 1);
    int g = clampi(trg[e], NNODES - 1);
    int r = clampi(rel[e], 3);
    unsigned pos = atomicAdd(&cursor[g * 4 + r], 1u);
    if (pos >= (unsigned)E) pos = E - 1;
    esrc[pos] = (unsigned)s;
    floatx4 v;
#pragma unroll
    for (int h = 0; h < 4; h++) {
        float val = s_src[s * 16 + h * 4 + r] + s_trg[g * 16 + h * 4 + r];
        val = val > 0.f ? val : 0.2f * val;
        v[h] = expf(val);
    }
    eexp[pos] = v;
}

// ---------------------------------------------------------------------------
// aggregation: one WAVE per bin (n,r). proj (n, r, h, f): per edge ONE
// contiguous 512B wave load. agg layout (bin, h, f) bf16.
// ---------------------------------------------------------------------------
__global__ __launch_bounds__(256) void rowagg2_k(const unsigned* __restrict__ offsets,
                                                 const unsigned* __restrict__ esrc,
                                                 const floatx4* __restrict__ eexp,
                                                 const unsigned short* __restrict__ proj,
                                                 unsigned short* __restrict__ agg) {
    int wave = threadIdx.x >> 6, lane = threadIdx.x & 63;
    int bin = blockIdx.x * 4 + wave;
    if (bin >= NBINS) return;
    int r = bin & 3;
    int h = lane >> 4;
    unsigned beg = offsets[bin], end = offsets[bin + 1];

    float a0 = 0.f, a1 = 0.f, a2 = 0.f, a3 = 0.f, den = 0.f;
    for (unsigned i = beg; i < end; i++) {
        unsigned s = esrc[i];
        floatx4 pe = eexp[i];
        float p = pe[h];
        const short4v* pp = (const short4v*)(proj + (size_t)s * 1024 + r * 256) + lane;
        short4v v = *pp;
        den += p;
        a0 = fmaf(p, bf2f((unsigned short)v[0]), a0);
        a1 = fmaf(p, bf2f((unsigned short)v[1]), a1);
        a2 = fmaf(p, bf2f((unsigned short)v[2]), a2);
        a3 = fmaf(p, bf2f((unsigned short)v[3]), a3);
    }
    float inv = 1.f / (den + 1e-16f);
    short4v o;
    o[0] = (short)f2bf(a0 * inv);
    o[1] = (short)f2bf(a1 * inv);
    o[2] = (short)f2bf(a2 * inv);
    o[3] = (short)f2bf(a3 * inv);
    *((short4v*)(agg + (size_t)bin * 256) + lane) = o;
}

// ---------------------------------------------------------------------------
// MFMA MLP
// ---------------------------------------------------------------------------
__global__ __launch_bounds__(256, 2) void mlp_mfma_k(const unsigned short* __restrict__ agg,
                                                     const float* __restrict__ wf,
                                                     float* __restrict__ sc) {
    __shared__ float lds[4][16 * 68];
    const int wave = threadIdx.x >> 6;
    const int lane = threadIdx.x & 63;
    const int l15 = lane & 15, q = lane >> 4;
    float* L = lds[wave];

    short8 w1f[2][4], w2f[2][4];
#pragma unroll
    for (int ks = 0; ks < 2; ks++)
#pragma unroll
        for (int nt = 0; nt < 4; nt++) {
            w1f[ks][nt] = pack_bf16(wf + WF_W1 + (nt * 16 + l15) * 64 + ks * 32 + q * 8);
            w2f[ks][nt] = pack_bf16(wf + WF_W2 + (nt * 16 + l15) * 64 + ks * 32 + q * 8);
        }
    float b1v[4], b2v[4], w3v[4];
#pragma unroll
    for (int nt = 0; nt < 4; nt++) {
        b1v[nt] = wf[WF_B1 + nt * 16 + l15];
        b2v[nt] = wf[WF_B2 + nt * 16 + l15];
        w3v[nt] = wf[WF_W3 + nt * 16 + l15];
    }
    float b3v = wf[WF_B3];

    int wave_id = blockIdx.x * 4 + wave;
#pragma unroll 1
    for (int t = 0; t < 4; t++) {
        int row0 = (wave_id * 4 + t) * 16;
        short8 a1[2];
#pragma unroll
        for (int ks = 0; ks < 2; ks++)
            a1[ks] = *(const short8*)(agg + (size_t)(row0 + l15) * 64 + ks * 32 + q * 8);
        floatx4 acc1[4];
#pragma unroll
        for (int nt = 0; nt < 4; nt++) {
            acc1[nt] = (floatx4){0.f, 0.f, 0.f, 0.f};
            acc1[nt] = __builtin_amdgcn_mfma_f32_16x16x32_bf16(a1[0], w1f[0][nt], acc1[nt], 0, 0, 0);
            acc1[nt] = __builtin_amdgcn_mfma_f32_16x16x32_bf16(a1[1], w1f[1][nt], acc1[nt], 0, 0, 0);
        }
        __syncthreads();
#pragma unroll
        for (int nt = 0; nt < 4; nt++)
#pragma unroll
            for (int rg = 0; rg < 4; rg++)
                L[(q * 4 + rg) * 68 + nt * 16 + l15] = fmaxf(acc1[nt][rg] + b1v[nt], 0.f);
        __syncthreads();
        short8 a2[2];
#pragma unroll
        for (int ks = 0; ks < 2; ks++) {
            short8 rr;
#pragma unroll
            for (int j = 0; j < 8; j++)
                rr[j] = (short)f2bf(L[l15 * 68 + ks * 32 + q * 8 + j]);
            a2[ks] = rr;
        }
        floatx4 acc2[4];
#pragma unroll
        for (int nt = 0; nt < 4; nt++) {
            acc2[nt] = (floatx4){0.f, 0.f, 0.f, 0.f};
            acc2[nt] = __builtin_amdgcn_mfma_f32_16x16x32_bf16(a2[0], w2f[0][nt], acc2[nt], 0, 0, 0);
            acc2[nt] = __builtin_amdgcn_mfma_f32_16x16x32_bf16(a2[1], w2f[1][nt], acc2[nt], 0, 0, 0);
        }
        float p[4];
#pragma unroll
        for (int rg = 0; rg < 4; rg++) {
            float s = 0.f;
#pragma unroll
            for (int nt = 0; nt < 4; nt++)
                s = fmaf(fmaxf(acc2[nt][rg] + b2v[nt], 0.f), w3v[nt], s);
            p[rg] = s;
        }
#pragma unroll
        for (int off = 1; off < 16; off <<= 1) {
#pragma unroll
            for (int rg = 0; rg < 4; rg++) p[rg] += __shfl_xor(p[rg], off);
        }
        if (l15 == 0) {
#pragma unroll
            for (int rg = 0; rg < 4; rg++) {
                float acc = p[rg] + b3v;
                float sp = fmaxf(acc, 0.f) + log1pf(expf(-fabsf(acc)));
                float m = acc * tanhf(sp);
                int s_id = row0 + q * 4 + rg;
                int n = s_id >> 4, r = (s_id >> 2) & 3, h = s_id & 3;
                sc[n * 16 + h * 4 + r] = m;
            }
        }
    }
}

// ---------------------------------------------------------------------------
// final: softmax over r, weighted sum, +skip(in d_out)+bias, ELU, LayerNorm
// ---------------------------------------------------------------------------
__global__ __launch_bounds__(256) void final_k(const unsigned short* __restrict__ agg,
                                               const float* __restrict__ sc,
                                               const float* __restrict__ wf,
                                               const unsigned* __restrict__ flag,
                                               unsigned short* __restrict__ out16,
                                               float* __restrict__ out32) {
    const bool f32 = (*flag != 0u);
    int n = blockIdx.x, t = threadIdx.x;
    int h = t >> 6, f = t & 63;
    float s0 = sc[n * 16 + h * 4 + 0];
    float s1 = sc[n * 16 + h * 4 + 1];
    float s2 = sc[n * 16 + h * 4 + 2];
    float s3 = sc[n * 16 + h * 4 + 3];
    float mx = fmaxf(fmaxf(s0, s1), fmaxf(s2, s3));
    float e0 = expf(s0 - mx), e1 = expf(s1 - mx), e2 = expf(s2 - mx), e3 = expf(s3 - mx);
    float inv = 1.f / (e0 + e1 + e2 + e3);
    size_t base = (size_t)n * 1024 + h * 64 + f;
    float a0 = bf2f(agg[base]);
    float a1 = bf2f(agg[base + 256]);
    float a2 = bf2f(agg[base + 512]);
    float a3 = bf2f(agg[base + 768]);
    float v = (e0 * a0 + e1 * a1 + e2 * a2 + e3 * a3) * inv;
    size_t oidx = (size_t)n * 256 + t;
    float skipv = f32 ? out32[oidx] : bf2f(out16[oidx]);
    v += skipv + wf[WF_BIAS + t];
    v = v > 0.f ? v : expm1f(v);

    float s = v, qq = v * v;
#pragma unroll
    for (int o = 1; o < 64; o <<= 1) {
        s += __shfl_xor(s, o);
        qq += __shfl_xor(qq, o);
    }
    __shared__ float red[8];
    __shared__ float stat[2];
    int wv = t >> 6, ln = t & 63;
    if (ln == 0) { red[wv] = s; red[4 + wv] = qq; }
    __syncthreads();
    if (t == 0) {
        float S = red[0] + red[1] + red[2] + red[3];
        float Q = red[4] + red[5] + red[6] + red[7];
        float mu = S * (1.f / 256.f);
        float var = fmaxf(Q * (1.f / 256.f) - mu * mu, 0.f);
        stat[0] = mu;
        stat[1] = rsqrtf(var + 1e-5f);
    }
    __syncthreads();
    float o = (v - stat[0]) * stat[1] * wf[WF_GAMMA + t] + wf[WF_BETA + t];
    if (f32) out32[oidx] = o;
    else     out16[oidx] = (unsigned short)f2bf(o);
}

// ---------------------------------------------------------------------------
// workspace layout (~226.85 MB). Overlays (serial-stream disjoint lifetimes):
//   xbf  -> agg region     (xbf read only by gemm_fused; agg written later)
//   wpbf/wsbf -> eexp head (weights read by gemm_fused; eexp written by fill_k)
// ---------------------------------------------------------------------------
extern "C" void kernel_launch(void* const* d_in, const int* in_sizes, int n_in,
                              void* d_out, int out_size, void* d_ws, size_t ws_size,
                              hipStream_t stream) {
    if (ws_size < 226900000) return;

    const void* x      = d_in[0];
    const int* src     = (const int*)d_in[1];
    const int* trg     = (const int*)d_in[2];
    const int* rel     = (const int*)d_in[3];
    const void* W_proj = d_in[5];
    const void* ssc    = d_in[6];
    const void* stc    = d_in[7];
    const void* W1     = d_in[8];
    const void* b1     = d_in[9];
    const void* W2     = d_in[10];
    const void* b2     = d_in[11];
    const void* W3     = d_in[12];
    const void* b3     = d_in[13];
    const void* W_skip = d_in[14];
    const void* bias   = d_in[15];
    const void* gamma  = d_in[16];
    const void* beta   = d_in[17];
    unsigned short* out16 = (unsigned short*)d_out;
    float* out32          = (float*)d_out;

    char* w = (char*)d_ws;
    unsigned short* proj = (unsigned short*)(w + 0);
    unsigned short* agg  = (unsigned short*)(w + 102400000);
    unsigned short* xbf  = (unsigned short*)(w + 102400000);  // overlay agg
    float* s_src         = (float*)(w + 204800000);
    float* s_trg         = (float*)(w + 208000000);
    floatx4* eexp        = (floatx4*)(w + 211200000);
    unsigned short* wpbf = (unsigned short*)(w + 211200000);  // overlay eexp head
    unsigned short* wsbf = (unsigned short*)(w + 212300000);  // overlay eexp head
    unsigned* esrc       = (unsigned*)(w + 219200000);
    unsigned* counts     = (unsigned*)(w + 221200000);
    unsigned* offsets    = (unsigned*)(w + 222000000);
    unsigned* cursor     = (unsigned*)(w + 222800016);
    float* sc            = (float*)(w + 223600016);
    float* wf            = (float*)(w + 226800016);  // 11204 floats = 44816 B
    unsigned* flag       = (unsigned*)(w + 226844840);
    unsigned* bsum       = (unsigned*)(w + 226844848);

    hipMemsetAsync(counts, 0, NBINS * 4, stream);

    probe_k<<<1, 256, 0, stream>>>((const unsigned short*)x, flag);
    wconv_k<<<1, 1024, 0, stream>>>(W1, b1, W2, b2, W3, b3, ssc, stc, bias, gamma, beta,
                                    flag, wf);
    convbf_k<<<(MPAD * 256) / (8 * 256), 256, 0, stream>>>(x, xbf, NNODES * 256,
                                                           MPAD * 256, flag);
    convbf_k<<<128, 256, 0, stream>>>(W_proj, wpbf, 1024 * 256, 1024 * 256, flag);
    convbf_k<<<32, 256, 0, stream>>>(W_skip, wsbf, 256 * 256, 256 * 256, flag);
    // proj + skip + score dots, one pass over A; cg-split across gridDim.y;
    // swapped-MFMA vectorized nt-store epilogue
    gemm_fused_k<<<dim3(784, 5), 64, 0, stream>>>(xbf, wpbf, wsbf, proj, out16, out32,
                                                  wf, s_src, s_trg, flag);
    count_k<<<1954, 256, 0, stream>>>(trg, rel, counts, NEDGES);
    scan1_k<<<NSCANB, 256, 0, stream>>>(counts, offsets, bsum);
    scan2_k<<<1, 256, 0, stream>>>(bsum, offsets);
    scan3_k<<<NSCANB, 256, 0, stream>>>(offsets, cursor, bsum);
    fill_k<<<1954, 256, 0, stream>>>(src, trg, rel, s_src, s_trg, cursor, esrc, eexp, NEDGES);
    rowagg2_k<<<NBINS / 4, 256, 0, stream>>>(offsets, esrc, eexp, proj, agg);
    mlp_mfma_k<<<3125, 256, 0, stream>>>(agg, wf, sc);
    final_k<<<NNODES, 256, 0, stream>>>(agg, sc, wf, flag, out16, out32);
}

// Round 5
// 532.833 us; speedup vs baseline: 1.1841x; 1.1841x over previous
//
#include <hip/hip_runtime.h>

#define NNODES 50000
#define NEDGES 500000
#define NBINS  (NNODES * 4)
#define NSCANB 196   // ceil(NBINS / 1024)
#define MPAD   50176 // 784*64

// wf fp32 arena offsets (in floats). SSC is padded to a multiple of 4 so the
// per-nt score vectors (cell*64 + nt*16 + q*4) are 16B-aligned floatx4 loads.
#define WF_W1    0
#define WF_B1    4096
#define WF_W2    4160
#define WF_B2    8256
#define WF_W3    8320
#define WF_B3    8384
#define WF_SSC   8388
#define WF_STC   9412
#define WF_BIAS  10436
#define WF_GAMMA 10692
#define WF_BETA  10948
#define WF_TOT   11204

typedef __attribute__((ext_vector_type(8))) short short8;
typedef __attribute__((ext_vector_type(4))) short short4v;
typedef __attribute__((ext_vector_type(4))) float floatx4;
typedef __attribute__((ext_vector_type(4))) unsigned int uint4v;

__device__ __forceinline__ float bf2f(unsigned short u) {
    return __uint_as_float(((unsigned)u) << 16);
}
__device__ __forceinline__ unsigned f2bf(float f) {
    unsigned u = __float_as_uint(f);
    u += 0x7fffu + ((u >> 16) & 1u);
    return u >> 16;
}
__device__ __forceinline__ int clampi(int v, int hi) { return v < 0 ? 0 : (v > hi ? hi : v); }

__device__ __forceinline__ short8 pack_bf16(const float* p) {
    short8 r;
#pragma unroll
    for (int j = 0; j < 8; j++) r[j] = (short)f2bf(p[j]);
    return r;
}

// ---------------------------------------------------------------------------
// dtype probe: flag=1 means inputs are fp32
// ---------------------------------------------------------------------------
__global__ __launch_bounds__(256) void probe_k(const unsigned short* __restrict__ xs,
                                               unsigned* __restrict__ flag) {
    __shared__ unsigned cnt;
    if (threadIdx.x == 0) cnt = 0;
    __syncthreads();
    unsigned local = 0;
    for (int i = threadIdx.x; i < 8192; i += 256) {
        float v = bf2f(xs[i]);
        if (!(fabsf(v) < 1e10f)) local++;
    }
    atomicAdd(&cnt, local);
    __syncthreads();
    if (threadIdx.x == 0) *flag = (cnt > 256u) ? 1u : 0u;
}

// ---------------------------------------------------------------------------
// polymorphic small-param conversion into fp32 arena
// ---------------------------------------------------------------------------
__device__ __forceinline__ float ldf(const void* p, int i, bool f32) {
    return f32 ? ((const float*)p)[i] : bf2f(((const unsigned short*)p)[i]);
}

__global__ __launch_bounds__(1024) void wconv_k(const void* W1, const void* b1,
                                                const void* W2, const void* b2,
                                                const void* W3, const void* b3,
                                                const void* ssc, const void* stc,
                                                const void* bias, const void* gamma,
                                                const void* beta,
                                                const unsigned* __restrict__ flag,
                                                float* __restrict__ wf) {
    bool f32 = (*flag != 0u);
    for (int i = threadIdx.x; i < WF_TOT; i += 1024) {
        float v;
        if (i < WF_B1)          v = ldf(W1, i - WF_W1, f32);
        else if (i < WF_W2)     v = ldf(b1, i - WF_B1, f32);
        else if (i < WF_B2)     v = ldf(W2, i - WF_W2, f32);
        else if (i < WF_W3)     v = ldf(b2, i - WF_B2, f32);
        else if (i < WF_B3)     v = ldf(W3, i - WF_W3, f32);
        else if (i < WF_SSC) {  // b3 (size 1) + 3 floats of alignment pad
            int j = i - WF_B3;
            v = (j < 1) ? ldf(b3, j, f32) : 0.f;
        }
        else if (i < WF_STC)    v = ldf(ssc, i - WF_SSC, f32);
        else if (i < WF_BIAS)   v = ldf(stc, i - WF_STC, f32);
        else if (i < WF_GAMMA)  v = ldf(bias, i - WF_BIAS, f32);
        else if (i < WF_BETA)   v = ldf(gamma, i - WF_GAMMA, f32);
        else                    v = ldf(beta, i - WF_BETA, f32);
        wf[i] = v;
    }
}

// ---------------------------------------------------------------------------
// bulk matrix conversion (fp32|bf16 -> bf16), zero-padded to npad elems
// ---------------------------------------------------------------------------
__global__ __launch_bounds__(256) void convbf_k(const void* __restrict__ src,
                                                unsigned short* __restrict__ dst,
                                                int nelem, int npad,
                                                const unsigned* __restrict__ flag) {
    int i8 = (blockIdx.x * 256 + threadIdx.x) * 8;
    if (i8 >= npad) return;
    short8 o;
    if (i8 < nelem) {
        if (*flag) {
            const float* pf = (const float*)src + i8;
            floatx4 a = *(const floatx4*)pf;
            floatx4 b = *(const floatx4*)(pf + 4);
            o[0] = (short)f2bf(a[0]); o[1] = (short)f2bf(a[1]);
            o[2] = (short)f2bf(a[2]); o[3] = (short)f2bf(a[3]);
            o[4] = (short)f2bf(b[0]); o[5] = (short)f2bf(b[1]);
            o[6] = (short)f2bf(b[2]); o[7] = (short)f2bf(b[3]);
        } else {
            o = *(const short8*)((const unsigned short*)src + i8);
        }
    } else {
#pragma unroll
        for (int j = 0; j < 8; j++) o[j] = 0;
    }
    *(short8*)(dst + i8) = o;
}

// ---------------------------------------------------------------------------
// fused one-pass GEMM (R1 base: reg A-stripe, cg-split over gridDim.y) with
// SWAPPED MFMA operands: mfma(B_frag, A_frag) -> lane l15 = x-row, (q,rg) =
// weight-col. Each lane owns 4 CONTIGUOUS output cols -> proj stores short4v,
// skip stores floatx4. Plain stores (R4's nontemporal hint amplified
// WRITE_SIZE 168->294MB via partial-sector eviction with zero dur change).
// s_src/s_trg cell layout = r*4+h so fill_k gathers become floatx4.
// ---------------------------------------------------------------------------
__global__ __launch_bounds__(64) void gemm_fused_k(const unsigned short* __restrict__ A,
                                                   const unsigned short* __restrict__ Bp,
                                                   const unsigned short* __restrict__ Bs,
                                                   unsigned short* __restrict__ proj,
                                                   unsigned short* __restrict__ out16,
                                                   float* __restrict__ out32,
                                                   const float* __restrict__ wf,
                                                   float* __restrict__ s_src,
                                                   float* __restrict__ s_trg,
                                                   const unsigned* __restrict__ flag) {
    const bool cf32 = (*flag != 0u);
    const int lane = threadIdx.x & 63;
    const int l15 = lane & 15, q = lane >> 4;
    const int m0 = blockIdx.x * 64;
    const int cg0 = blockIdx.y * 4;   // 0,4,8,12 = proj groups; 16 = skip groups

    // A-stripe: 64 rows x 256 K in registers (128 VGPRs)
    short8 af[4][8];
#pragma unroll
    for (int mt = 0; mt < 4; mt++)
#pragma unroll
        for (int ks = 0; ks < 8; ks++)
            af[mt][ks] = *(const short8*)(A + (size_t)(m0 + mt * 16 + l15) * 256 + ks * 32 + q * 8);

    if (cg0 < 16) {
        // ---- proj columns (4 of 16) ----
#pragma unroll 1
        for (int cgi = 0; cgi < 4; cgi++) {
            const int cg = cg0 + cgi;
            floatx4 acc[4][4];
#pragma unroll
            for (int i = 0; i < 4; i++)
#pragma unroll
                for (int j = 0; j < 4; j++) acc[i][j] = (floatx4){0.f, 0.f, 0.f, 0.f};
#pragma unroll
            for (int ks = 0; ks < 8; ks++) {
                short8 bfr[4];
#pragma unroll
                for (int nt = 0; nt < 4; nt++)
                    bfr[nt] = *(const short8*)(Bp + (size_t)(cg * 64 + nt * 16 + l15) * 256 + ks * 32 + q * 8);
#pragma unroll
                for (int mt = 0; mt < 4; mt++)
#pragma unroll
                    for (int nt = 0; nt < 4; nt++)
                        acc[mt][nt] = __builtin_amdgcn_mfma_f32_16x16x32_bf16(bfr[nt], af[mt][ks],
                                                                             acc[mt][nt], 0, 0, 0);
            }
            const int h = cg >> 2, r = cg & 3;
            const int colbase = (r * 4 + h) * 64;   // proj (n,r,h,f) layout
            const int cell = r * 4 + h;             // s_src/s_trg (n,r,h) layout
            const int scell = h * 4 + r;            // score-weight cell in wf (h,r)
            floatx4 sa4[4], sb4[4];
#pragma unroll
            for (int nt = 0; nt < 4; nt++) {
                sa4[nt] = *(const floatx4*)(wf + WF_SSC + scell * 64 + nt * 16 + q * 4);
                sb4[nt] = *(const floatx4*)(wf + WF_STC + scell * 64 + nt * 16 + q * 4);
            }
#pragma unroll
            for (int mt = 0; mt < 4; mt++) {
                const int row = m0 + mt * 16 + l15;
                float pa = 0.f, pb = 0.f;
#pragma unroll
                for (int nt = 0; nt < 4; nt++) {
                    short4v sv;
#pragma unroll
                    for (int rg = 0; rg < 4; rg++) {
                        float v = acc[mt][nt][rg];
                        unsigned short vb = (unsigned short)f2bf(v);
                        sv[rg] = (short)vb;
                        float vr = bf2f(vb);   // match prior bf16-rounded score path
                        pa = fmaf(vr, sa4[nt][rg], pa);
                        pb = fmaf(vr, sb4[nt][rg], pb);
                    }
                    if (row < NNODES)
                        *(short4v*)(proj + (size_t)row * 1024 + colbase + nt * 16 + q * 4) = sv;
                }
                pa += __shfl_xor(pa, 16);
                pa += __shfl_xor(pa, 32);
                pb += __shfl_xor(pb, 16);
                pb += __shfl_xor(pb, 32);
                if (q == 0 && row < NNODES) {
                    s_src[row * 16 + cell] = pa;
                    s_trg[row * 16 + cell] = pb;
                }
            }
        }
    } else {
        // ---- skip columns (all 4) ----
#pragma unroll 1
        for (int cg = 0; cg < 4; cg++) {
            floatx4 acc[4][4];
#pragma unroll
            for (int i = 0; i < 4; i++)
#pragma unroll
                for (int j = 0; j < 4; j++) acc[i][j] = (floatx4){0.f, 0.f, 0.f, 0.f};
#pragma unroll
            for (int ks = 0; ks < 8; ks++) {
                short8 bfr[4];
#pragma unroll
                for (int nt = 0; nt < 4; nt++)
                    bfr[nt] = *(const short8*)(Bs + (size_t)(cg * 64 + nt * 16 + l15) * 256 + ks * 32 + q * 8);
#pragma unroll
                for (int mt = 0; mt < 4; mt++)
#pragma unroll
                    for (int nt = 0; nt < 4; nt++)
                        acc[mt][nt] = __builtin_amdgcn_mfma_f32_16x16x32_bf16(bfr[nt], af[mt][ks],
                                                                             acc[mt][nt], 0, 0, 0);
            }
#pragma unroll
            for (int mt = 0; mt < 4; mt++) {
                const int row = m0 + mt * 16 + l15;
                if (row >= NNODES) continue;
#pragma unroll
                for (int nt = 0; nt < 4; nt++) {
                    if (cf32) {
                        floatx4 o = acc[mt][nt];
                        *(floatx4*)(out32 + (size_t)row * 256 + cg * 64 + nt * 16 + q * 4) = o;
                    } else {
                        short4v sv;
#pragma unroll
                        for (int rg = 0; rg < 4; rg++)
                            sv[rg] = (short)f2bf(acc[mt][nt][rg]);
                        *(short4v*)(out16 + (size_t)row * 256 + cg * 64 + nt * 16 + q * 4) = sv;
                    }
                }
            }
        }
    }
}

// ---------------------------------------------------------------------------
// CSR build: count -> hierarchical scan -> fill
// ---------------------------------------------------------------------------
__global__ __launch_bounds__(256) void count_k(const int* __restrict__ trg,
                                               const int* __restrict__ rel,
                                               unsigned* __restrict__ counts, int E) {
    int e = blockIdx.x * 256 + threadIdx.x;
    if (e >= E) return;
    int g = clampi(trg[e], NNODES - 1);
    int r = clampi(rel[e], 3);
    atomicAdd(&counts[g * 4 + r], 1u);
}

__global__ __launch_bounds__(256) void scan1_k(const unsigned* __restrict__ counts,
                                               unsigned* __restrict__ offsets,
                                               unsigned* __restrict__ bsum) {
    __shared__ unsigned ts[256];
    int t = threadIdx.x;
    int base = blockIdx.x * 1024 + t * 4;
    uint4v c = {0u, 0u, 0u, 0u};
    if (base + 3 < NBINS) c = *(const uint4v*)(counts + base);
    else {
#pragma unroll
        for (int j = 0; j < 4; j++) c[j] = (base + j < NBINS) ? counts[base + j] : 0u;
    }
    ts[t] = c[0] + c[1] + c[2] + c[3];
    __syncthreads();
    for (int off = 1; off < 256; off <<= 1) {
        unsigned v = (t >= off) ? ts[t - off] : 0u;
        __syncthreads();
        ts[t] += v;
        __syncthreads();
    }
    unsigned pre = (t == 0) ? 0u : ts[t - 1];
    uint4v o;
    o[0] = pre;
    o[1] = pre + c[0];
    o[2] = pre + c[0] + c[1];
    o[3] = pre + c[0] + c[1] + c[2];
    if (base + 3 < NBINS) *(uint4v*)(offsets + base) = o;
    else {
#pragma unroll
        for (int j = 0; j < 4; j++) if (base + j < NBINS) offsets[base + j] = o[j];
    }
    if (t == 255) bsum[blockIdx.x] = ts[255];
}

__global__ __launch_bounds__(256) void scan2_k(unsigned* __restrict__ bsum,
                                               unsigned* __restrict__ offsets) {
    __shared__ unsigned ts[256];
    int t = threadIdx.x;
    unsigned v = (t < NSCANB) ? bsum[t] : 0u;
    ts[t] = v;
    __syncthreads();
    for (int off = 1; off < 256; off <<= 1) {
        unsigned u = (t >= off) ? ts[t - off] : 0u;
        __syncthreads();
        ts[t] += u;
        __syncthreads();
    }
    if (t < NSCANB) bsum[t] = (t == 0) ? 0u : ts[t - 1];
    if (t == 255) offsets[NBINS] = ts[255];
}

__global__ __launch_bounds__(256) void scan3_k(unsigned* __restrict__ offsets,
                                               unsigned* __restrict__ cursor,
                                               const unsigned* __restrict__ bsum) {
    int t = threadIdx.x;
    unsigned base = bsum[blockIdx.x];
    int idx = blockIdx.x * 1024 + t * 4;
    if (idx + 3 < NBINS) {
        uint4v o = *(const uint4v*)(offsets + idx);
        o[0] += base; o[1] += base; o[2] += base; o[3] += base;
        *(uint4v*)(offsets + idx) = o;
        *(uint4v*)(cursor + idx) = o;
    } else {
#pragma unroll
        for (int j = 0; j < 4; j++)
            if (idx + j < NBINS) {
                unsigned v = offsets[idx + j] + base;
                offsets[idx + j] = v;
                cursor[idx + j] = v;
            }
    }
}

__global__ __launch_bounds__(256) void fill_k(const int* __restrict__ src,
                                              const int* __restrict__ trg,
                                              const int* __restrict__ rel,
                                              const float* __restrict__ s_src,
                                              const float* __restrict__ s_trg,
                                              unsigned* __restrict__ cursor,
                                              unsigned* __restrict__ esrc,
                                              floatx4* __restrict__ eexp, int E) {
    int e = blockIdx.x * 256 + threadIdx.x;
    if (e >= E) return;
    int s = clampi(src[e], NNODES - 1);
    int g = clampi(trg[e], NNODES - 1);
    int r = clampi(rel[e], 3);
    unsigned pos = atomicAdd(&cursor[g * 4 + r], 1u);
    if (pos >= (unsigned)E) pos = E - 1;
    esrc[pos] = (unsigned)s;
    // s_src/s_trg layout (n, r, h): one floatx4 per gather
    floatx4 aa = *(const floatx4*)(s_src + s * 16 + r * 4);
    floatx4 bb = *(const floatx4*)(s_trg + g * 16 + r * 4);
    floatx4 v;
#pragma unroll
    for (int h = 0; h < 4; h++) {
        float val = aa[h] + bb[h];
        val = val > 0.f ? val : 0.2f * val;
        v[h] = expf(val);
    }
    eexp[pos] = v;
}

// ---------------------------------------------------------------------------
// aggregation: one WAVE per bin (n,r). proj (n, r, h, f): per edge ONE
// contiguous 512B wave load. 2-wide software pipeline so two edges' gathers
// are in flight together (bins avg 2.5 edges; pure gather-latency bound).
// agg layout (bin, h, f) bf16.
// ---------------------------------------------------------------------------
__global__ __launch_bounds__(256) void rowagg2_k(const unsigned* __restrict__ offsets,
                                                 const unsigned* __restrict__ esrc,
                                                 const floatx4* __restrict__ eexp,
                                                 const unsigned short* __restrict__ proj,
                                                 unsigned short* __restrict__ agg) {
    int wave = threadIdx.x >> 6, lane = threadIdx.x & 63;
    int bin = blockIdx.x * 4 + wave;
    if (bin >= NBINS) return;
    int r = bin & 3;
    int h = lane >> 4;
    unsigned beg = offsets[bin], end = offsets[bin + 1];

    float a0 = 0.f, a1 = 0.f, a2 = 0.f, a3 = 0.f, den = 0.f;
    unsigned i = beg;
    for (; i + 2 <= end; i += 2) {
        unsigned s0 = esrc[i], s1 = esrc[i + 1];
        floatx4 pe0 = eexp[i], pe1 = eexp[i + 1];
        short4v v0 = *((const short4v*)(proj + (size_t)s0 * 1024 + r * 256) + lane);
        short4v v1 = *((const short4v*)(proj + (size_t)s1 * 1024 + r * 256) + lane);
        float p0 = pe0[h], p1 = pe1[h];
        den += p0 + p1;
        a0 = fmaf(p0, bf2f((unsigned short)v0[0]), a0);
        a1 = fmaf(p0, bf2f((unsigned short)v0[1]), a1);
        a2 = fmaf(p0, bf2f((unsigned short)v0[2]), a2);
        a3 = fmaf(p0, bf2f((unsigned short)v0[3]), a3);
        a0 = fmaf(p1, bf2f((unsigned short)v1[0]), a0);
        a1 = fmaf(p1, bf2f((unsigned short)v1[1]), a1);
        a2 = fmaf(p1, bf2f((unsigned short)v1[2]), a2);
        a3 = fmaf(p1, bf2f((unsigned short)v1[3]), a3);
    }
    if (i < end) {
        unsigned s0 = esrc[i];
        floatx4 pe0 = eexp[i];
        short4v v0 = *((const short4v*)(proj + (size_t)s0 * 1024 + r * 256) + lane);
        float p0 = pe0[h];
        den += p0;
        a0 = fmaf(p0, bf2f((unsigned short)v0[0]), a0);
        a1 = fmaf(p0, bf2f((unsigned short)v0[1]), a1);
        a2 = fmaf(p0, bf2f((unsigned short)v0[2]), a2);
        a3 = fmaf(p0, bf2f((unsigned short)v0[3]), a3);
    }
    float inv = 1.f / (den + 1e-16f);
    short4v o;
    o[0] = (short)f2bf(a0 * inv);
    o[1] = (short)f2bf(a1 * inv);
    o[2] = (short)f2bf(a2 * inv);
    o[3] = (short)f2bf(a3 * inv);
    *((short4v*)(agg + (size_t)bin * 256) + lane) = o;
}

// ---------------------------------------------------------------------------
// MFMA MLP. LDS slice is wave-private -> NO block barriers needed (compiler
// inserts lgkmcnt waits for same-wave LDS write->read ordering).
// ---------------------------------------------------------------------------
__global__ __launch_bounds__(256, 2) void mlp_mfma_k(const unsigned short* __restrict__ agg,
                                                     const float* __restrict__ wf,
                                                     float* __restrict__ sc) {
    __shared__ float lds[4][16 * 68];
    const int wave = threadIdx.x >> 6;
    const int lane = threadIdx.x & 63;
    const int l15 = lane & 15, q = lane >> 4;
    float* L = lds[wave];

    short8 w1f[2][4], w2f[2][4];
#pragma unroll
    for (int ks = 0; ks < 2; ks++)
#pragma unroll
        for (int nt = 0; nt < 4; nt++) {
            w1f[ks][nt] = pack_bf16(wf + WF_W1 + (nt * 16 + l15) * 64 + ks * 32 + q * 8);
            w2f[ks][nt] = pack_bf16(wf + WF_W2 + (nt * 16 + l15) * 64 + ks * 32 + q * 8);
        }
    float b1v[4], b2v[4], w3v[4];
#pragma unroll
    for (int nt = 0; nt < 4; nt++) {
        b1v[nt] = wf[WF_B1 + nt * 16 + l15];
        b2v[nt] = wf[WF_B2 + nt * 16 + l15];
        w3v[nt] = wf[WF_W3 + nt * 16 + l15];
    }
    float b3v = wf[WF_B3];

    int wave_id = blockIdx.x * 4 + wave;
#pragma unroll 1
    for (int t = 0; t < 4; t++) {
        int row0 = (wave_id * 4 + t) * 16;
        short8 a1[2];
#pragma unroll
        for (int ks = 0; ks < 2; ks++)
            a1[ks] = *(const short8*)(agg + (size_t)(row0 + l15) * 64 + ks * 32 + q * 8);
        floatx4 acc1[4];
#pragma unroll
        for (int nt = 0; nt < 4; nt++) {
            acc1[nt] = (floatx4){0.f, 0.f, 0.f, 0.f};
            acc1[nt] = __builtin_amdgcn_mfma_f32_16x16x32_bf16(a1[0], w1f[0][nt], acc1[nt], 0, 0, 0);
            acc1[nt] = __builtin_amdgcn_mfma_f32_16x16x32_bf16(a1[1], w1f[1][nt], acc1[nt], 0, 0, 0);
        }
#pragma unroll
        for (int nt = 0; nt < 4; nt++)
#pragma unroll
            for (int rg = 0; rg < 4; rg++)
                L[(q * 4 + rg) * 68 + nt * 16 + l15] = fmaxf(acc1[nt][rg] + b1v[nt], 0.f);
        short8 a2[2];
#pragma unroll
        for (int ks = 0; ks < 2; ks++) {
            short8 rr;
#pragma unroll
            for (int j = 0; j < 8; j++)
                rr[j] = (short)f2bf(L[l15 * 68 + ks * 32 + q * 8 + j]);
            a2[ks] = rr;
        }
        floatx4 acc2[4];
#pragma unroll
        for (int nt = 0; nt < 4; nt++) {
            acc2[nt] = (floatx4){0.f, 0.f, 0.f, 0.f};
            acc2[nt] = __builtin_amdgcn_mfma_f32_16x16x32_bf16(a2[0], w2f[0][nt], acc2[nt], 0, 0, 0);
            acc2[nt] = __builtin_amdgcn_mfma_f32_16x16x32_bf16(a2[1], w2f[1][nt], acc2[nt], 0, 0, 0);
        }
        float p[4];
#pragma unroll
        for (int rg = 0; rg < 4; rg++) {
            float s = 0.f;
#pragma unroll
            for (int nt = 0; nt < 4; nt++)
                s = fmaf(fmaxf(acc2[nt][rg] + b2v[nt], 0.f), w3v[nt], s);
            p[rg] = s;
        }
#pragma unroll
        for (int off = 1; off < 16; off <<= 1) {
#pragma unroll
            for (int rg = 0; rg < 4; rg++) p[rg] += __shfl_xor(p[rg], off);
        }
        if (l15 == 0) {
#pragma unroll
            for (int rg = 0; rg < 4; rg++) {
                float acc = p[rg] + b3v;
                float sp = fmaxf(acc, 0.f) + log1pf(expf(-fabsf(acc)));
                float m = acc * tanhf(sp);
                int s_id = row0 + q * 4 + rg;
                int n = s_id >> 4, r = (s_id >> 2) & 3, h = s_id & 3;
                sc[n * 16 + h * 4 + r] = m;
            }
        }
    }
}

// ---------------------------------------------------------------------------
// final: one WAVE per node (4/block). Lane owns head h = lane>>4 and 4
// contiguous cols c0..c0+3 (c0 = h*64 + (lane&15)*4): softmax over r,
// weighted agg sum, +skip+bias, ELU, LayerNorm via pure shfl reduce.
// No LDS, no barriers, all loads/stores vectorized.
// ---------------------------------------------------------------------------
__global__ __launch_bounds__(256) void final_k(const unsigned short* __restrict__ agg,
                                               const float* __restrict__ sc,
                                               const float* __restrict__ wf,
                                               const unsigned* __restrict__ flag,
                                               unsigned short* __restrict__ out16,
                                               float* __restrict__ out32) {
    const bool f32 = (*flag != 0u);
    const int wave = threadIdx.x >> 6, lane = threadIdx.x & 63;
    const int n = blockIdx.x * 4 + wave;
    const int h = lane >> 4;
    const int c0 = h * 64 + (lane & 15) * 4;

    // softmax weights over r for this lane's head (broadcast floatx4)
    floatx4 sv = *(const floatx4*)(sc + n * 16 + h * 4);
    float mx = fmaxf(fmaxf(sv[0], sv[1]), fmaxf(sv[2], sv[3]));
    float e0 = expf(sv[0] - mx), e1 = expf(sv[1] - mx);
    float e2 = expf(sv[2] - mx), e3 = expf(sv[3] - mx);
    float inv = 1.f / (e0 + e1 + e2 + e3);
    float er[4] = {e0 * inv, e1 * inv, e2 * inv, e3 * inv};

    float acc4[4] = {0.f, 0.f, 0.f, 0.f};
#pragma unroll
    for (int r = 0; r < 4; r++) {
        short4v av = *(const short4v*)(agg + (size_t)n * 1024 + r * 256 + c0);
        float e = er[r];
        acc4[0] = fmaf(e, bf2f((unsigned short)av[0]), acc4[0]);
        acc4[1] = fmaf(e, bf2f((unsigned short)av[1]), acc4[1]);
        acc4[2] = fmaf(e, bf2f((unsigned short)av[2]), acc4[2]);
        acc4[3] = fmaf(e, bf2f((unsigned short)av[3]), acc4[3]);
    }

    const size_t ob = (size_t)n * 256 + c0;
    float v[4];
    floatx4 bi = *(const floatx4*)(wf + WF_BIAS + c0);
    if (f32) {
        floatx4 sk = *(const floatx4*)(out32 + ob);
#pragma unroll
        for (int j = 0; j < 4; j++) v[j] = acc4[j] + sk[j] + bi[j];
    } else {
        short4v sk = *(const short4v*)(out16 + ob);
#pragma unroll
        for (int j = 0; j < 4; j++) v[j] = acc4[j] + bf2f((unsigned short)sk[j]) + bi[j];
    }
#pragma unroll
    for (int j = 0; j < 4; j++) v[j] = v[j] > 0.f ? v[j] : expm1f(v[j]);

    float s = v[0] + v[1] + v[2] + v[3];
    float qq = v[0] * v[0] + v[1] * v[1] + v[2] * v[2] + v[3] * v[3];
#pragma unroll
    for (int o = 1; o < 64; o <<= 1) {
        s += __shfl_xor(s, o);
        qq += __shfl_xor(qq, o);
    }
    float mu = s * (1.f / 256.f);
    float var = fmaxf(qq * (1.f / 256.f) - mu * mu, 0.f);
    float rstd = rsqrtf(var + 1e-5f);

    floatx4 ga = *(const floatx4*)(wf + WF_GAMMA + c0);
    floatx4 be = *(const floatx4*)(wf + WF_BETA + c0);
    if (f32) {
        floatx4 o4;
#pragma unroll
        for (int j = 0; j < 4; j++) o4[j] = (v[j] - mu) * rstd * ga[j] + be[j];
        *(floatx4*)(out32 + ob) = o4;
    } else {
        short4v o4;
#pragma unroll
        for (int j = 0; j < 4; j++) o4[j] = (short)f2bf((v[j] - mu) * rstd * ga[j] + be[j]);
        *(short4v*)(out16 + ob) = o4;
    }
}

// ---------------------------------------------------------------------------
// workspace layout (~226.85 MB). Overlays (serial-stream disjoint lifetimes):
//   xbf  -> agg region     (xbf read only by gemm_fused; agg written later)
//   wpbf/wsbf -> eexp head (weights read by gemm_fused; eexp written by fill_k)
// ---------------------------------------------------------------------------
extern "C" void kernel_launch(void* const* d_in, const int* in_sizes, int n_in,
                              void* d_out, int out_size, void* d_ws, size_t ws_size,
                              hipStream_t stream) {
    if (ws_size < 226900000) return;

    const void* x      = d_in[0];
    const int* src     = (const int*)d_in[1];
    const int* trg     = (const int*)d_in[2];
    const int* rel     = (const int*)d_in[3];
    const void* W_proj = d_in[5];
    const void* ssc    = d_in[6];
    const void* stc    = d_in[7];
    const void* W1     = d_in[8];
    const void* b1     = d_in[9];
    const void* W2     = d_in[10];
    const void* b2     = d_in[11];
    const void* W3     = d_in[12];
    const void* b3     = d_in[13];
    const void* W_skip = d_in[14];
    const void* bias   = d_in[15];
    const void* gamma  = d_in[16];
    const void* beta   = d_in[17];
    unsigned short* out16 = (unsigned short*)d_out;
    float* out32          = (float*)d_out;

    char* w = (char*)d_ws;
    unsigned short* proj = (unsigned short*)(w + 0);
    unsigned short* agg  = (unsigned short*)(w + 102400000);
    unsigned short* xbf  = (unsigned short*)(w + 102400000);  // overlay agg
    float* s_src         = (float*)(w + 204800000);
    float* s_trg         = (float*)(w + 208000000);
    floatx4* eexp        = (floatx4*)(w + 211200000);
    unsigned short* wpbf = (unsigned short*)(w + 211200000);  // overlay eexp head
    unsigned short* wsbf = (unsigned short*)(w + 212300000);  // overlay eexp head
    unsigned* esrc       = (unsigned*)(w + 219200000);
    unsigned* counts     = (unsigned*)(w + 221200000);
    unsigned* offsets    = (unsigned*)(w + 222000000);
    unsigned* cursor     = (unsigned*)(w + 222800016);
    float* sc            = (float*)(w + 223600016);
    float* wf            = (float*)(w + 226800016);  // 11204 floats = 44816 B
    unsigned* flag       = (unsigned*)(w + 226844840);
    unsigned* bsum       = (unsigned*)(w + 226844848);

    hipMemsetAsync(counts, 0, NBINS * 4, stream);

    probe_k<<<1, 256, 0, stream>>>((const unsigned short*)x, flag);
    wconv_k<<<1, 1024, 0, stream>>>(W1, b1, W2, b2, W3, b3, ssc, stc, bias, gamma, beta,
                                    flag, wf);
    convbf_k<<<(MPAD * 256) / (8 * 256), 256, 0, stream>>>(x, xbf, NNODES * 256,
                                                           MPAD * 256, flag);
    convbf_k<<<128, 256, 0, stream>>>(W_proj, wpbf, 1024 * 256, 1024 * 256, flag);
    convbf_k<<<32, 256, 0, stream>>>(W_skip, wsbf, 256 * 256, 256 * 256, flag);
    // proj + skip + score dots, one pass over A; cg-split across gridDim.y;
    // swapped-MFMA vectorized epilogue (plain stores)
    gemm_fused_k<<<dim3(784, 5), 64, 0, stream>>>(xbf, wpbf, wsbf, proj, out16, out32,
                                                  wf, s_src, s_trg, flag);
    count_k<<<1954, 256, 0, stream>>>(trg, rel, counts, NEDGES);
    scan1_k<<<NSCANB, 256, 0, stream>>>(counts, offsets, bsum);
    scan2_k<<<1, 256, 0, stream>>>(bsum, offsets);
    scan3_k<<<NSCANB, 256, 0, stream>>>(offsets, cursor, bsum);
    fill_k<<<1954, 256, 0, stream>>>(src, trg, rel, s_src, s_trg, cursor, esrc, eexp, NEDGES);
    rowagg2_k<<<NBINS / 4, 256, 0, stream>>>(offsets, esrc, eexp, proj, agg);
    mlp_mfma_k<<<3125, 256, 0, stream>>>(agg, wf, sc);
    final_k<<<12500, 256, 0, stream>>>(agg, sc, wf, flag, out16, out32);
}

// Round 6
// 509.023 us; speedup vs baseline: 1.2395x; 1.0468x over previous
//
#include <hip/hip_runtime.h>

#define NNODES 50000
#define NEDGES 500000
#define NBINS  (NNODES * 4)
#define NSCANB 196   // ceil(NBINS / 1024)
#define MPAD   50176 // 784*64

// wf fp32 arena offsets (in floats). SSC is padded to a multiple of 4 so the
// per-nt score vectors (cell*64 + nt*16 + q*4) are 16B-aligned floatx4 loads.
#define WF_W1    0
#define WF_B1    4096
#define WF_W2    4160
#define WF_B2    8256
#define WF_W3    8320
#define WF_B3    8384
#define WF_SSC   8388
#define WF_STC   9412
#define WF_BIAS  10436
#define WF_GAMMA 10692
#define WF_BETA  10948
#define WF_TOT   11204
// bf16-packed W1||W2 (row-major, 4096 each) appended for MFMA fragment loads
#define WB_TOT   8192

typedef __attribute__((ext_vector_type(8))) short short8;
typedef __attribute__((ext_vector_type(4))) short short4v;
typedef __attribute__((ext_vector_type(4))) float floatx4;
typedef __attribute__((ext_vector_type(4))) unsigned int uint4v;

__device__ __forceinline__ float bf2f(unsigned short u) {
    return __uint_as_float(((unsigned)u) << 16);
}
__device__ __forceinline__ unsigned f2bf(float f) {
    unsigned u = __float_as_uint(f);
    u += 0x7fffu + ((u >> 16) & 1u);
    return u >> 16;
}
__device__ __forceinline__ int clampi(int v, int hi) { return v < 0 ? 0 : (v > hi ? hi : v); }

// ---------------------------------------------------------------------------
// dtype probe: flag=1 means inputs are fp32
// ---------------------------------------------------------------------------
__global__ __launch_bounds__(256) void probe_k(const unsigned short* __restrict__ xs,
                                               unsigned* __restrict__ flag) {
    __shared__ unsigned cnt;
    if (threadIdx.x == 0) cnt = 0;
    __syncthreads();
    unsigned local = 0;
    for (int i = threadIdx.x; i < 8192; i += 256) {
        float v = bf2f(xs[i]);
        if (!(fabsf(v) < 1e10f)) local++;
    }
    atomicAdd(&cnt, local);
    __syncthreads();
    if (threadIdx.x == 0) *flag = (cnt > 256u) ? 1u : 0u;
}

// ---------------------------------------------------------------------------
// polymorphic small-param conversion into fp32 arena + bf16 W1/W2 pack
// ---------------------------------------------------------------------------
__device__ __forceinline__ float ldf(const void* p, int i, bool f32) {
    return f32 ? ((const float*)p)[i] : bf2f(((const unsigned short*)p)[i]);
}

__global__ __launch_bounds__(1024) void wconv_k(const void* W1, const void* b1,
                                                const void* W2, const void* b2,
                                                const void* W3, const void* b3,
                                                const void* ssc, const void* stc,
                                                const void* bias, const void* gamma,
                                                const void* beta,
                                                const unsigned* __restrict__ flag,
                                                float* __restrict__ wf,
                                                unsigned short* __restrict__ wbf16) {
    bool f32 = (*flag != 0u);
    for (int i = threadIdx.x; i < WF_TOT + WB_TOT; i += 1024) {
        if (i >= WF_TOT) {
            int j = i - WF_TOT;
            float v = (j < 4096) ? ldf(W1, j, f32) : ldf(W2, j - 4096, f32);
            wbf16[j] = (unsigned short)f2bf(v);
            continue;
        }
        float v;
        if (i < WF_B1)          v = ldf(W1, i - WF_W1, f32);
        else if (i < WF_W2)     v = ldf(b1, i - WF_B1, f32);
        else if (i < WF_B2)     v = ldf(W2, i - WF_W2, f32);
        else if (i < WF_W3)     v = ldf(b2, i - WF_B2, f32);
        else if (i < WF_B3)     v = ldf(W3, i - WF_W3, f32);
        else if (i < WF_SSC) {  // b3 (size 1) + 3 floats of alignment pad
            int j = i - WF_B3;
            v = (j < 1) ? ldf(b3, j, f32) : 0.f;
        }
        else if (i < WF_STC)    v = ldf(ssc, i - WF_SSC, f32);
        else if (i < WF_BIAS)   v = ldf(stc, i - WF_STC, f32);
        else if (i < WF_GAMMA)  v = ldf(bias, i - WF_BIAS, f32);
        else if (i < WF_BETA)   v = ldf(gamma, i - WF_GAMMA, f32);
        else                    v = ldf(beta, i - WF_BETA, f32);
        wf[i] = v;
    }
}

// ---------------------------------------------------------------------------
// bulk matrix conversion (fp32|bf16 -> bf16), zero-padded to npad elems
// ---------------------------------------------------------------------------
__global__ __launch_bounds__(256) void convbf_k(const void* __restrict__ src,
                                                unsigned short* __restrict__ dst,
                                                int nelem, int npad,
                                                const unsigned* __restrict__ flag) {
    int i8 = (blockIdx.x * 256 + threadIdx.x) * 8;
    if (i8 >= npad) return;
    short8 o;
    if (i8 < nelem) {
        if (*flag) {
            const float* pf = (const float*)src + i8;
            floatx4 a = *(const floatx4*)pf;
            floatx4 b = *(const floatx4*)(pf + 4);
            o[0] = (short)f2bf(a[0]); o[1] = (short)f2bf(a[1]);
            o[2] = (short)f2bf(a[2]); o[3] = (short)f2bf(a[3]);
            o[4] = (short)f2bf(b[0]); o[5] = (short)f2bf(b[1]);
            o[6] = (short)f2bf(b[2]); o[7] = (short)f2bf(b[3]);
        } else {
            o = *(const short8*)((const unsigned short*)src + i8);
        }
    } else {
#pragma unroll
        for (int j = 0; j < 8; j++) o[j] = 0;
    }
    *(short8*)(dst + i8) = o;
}

// ---------------------------------------------------------------------------
// fused one-pass GEMM (unchanged from R5: swapped MFMA operands, vectorized
// plain-store epilogue, cg-split over gridDim.y). 133 us, stable.
// ---------------------------------------------------------------------------
__global__ __launch_bounds__(64) void gemm_fused_k(const unsigned short* __restrict__ A,
                                                   const unsigned short* __restrict__ Bp,
                                                   const unsigned short* __restrict__ Bs,
                                                   unsigned short* __restrict__ proj,
                                                   unsigned short* __restrict__ out16,
                                                   float* __restrict__ out32,
                                                   const float* __restrict__ wf,
                                                   float* __restrict__ s_src,
                                                   float* __restrict__ s_trg,
                                                   const unsigned* __restrict__ flag) {
    const bool cf32 = (*flag != 0u);
    const int lane = threadIdx.x & 63;
    const int l15 = lane & 15, q = lane >> 4;
    const int m0 = blockIdx.x * 64;
    const int cg0 = blockIdx.y * 4;   // 0,4,8,12 = proj groups; 16 = skip groups

    short8 af[4][8];
#pragma unroll
    for (int mt = 0; mt < 4; mt++)
#pragma unroll
        for (int ks = 0; ks < 8; ks++)
            af[mt][ks] = *(const short8*)(A + (size_t)(m0 + mt * 16 + l15) * 256 + ks * 32 + q * 8);

    if (cg0 < 16) {
#pragma unroll 1
        for (int cgi = 0; cgi < 4; cgi++) {
            const int cg = cg0 + cgi;
            floatx4 acc[4][4];
#pragma unroll
            for (int i = 0; i < 4; i++)
#pragma unroll
                for (int j = 0; j < 4; j++) acc[i][j] = (floatx4){0.f, 0.f, 0.f, 0.f};
#pragma unroll
            for (int ks = 0; ks < 8; ks++) {
                short8 bfr[4];
#pragma unroll
                for (int nt = 0; nt < 4; nt++)
                    bfr[nt] = *(const short8*)(Bp + (size_t)(cg * 64 + nt * 16 + l15) * 256 + ks * 32 + q * 8);
#pragma unroll
                for (int mt = 0; mt < 4; mt++)
#pragma unroll
                    for (int nt = 0; nt < 4; nt++)
                        acc[mt][nt] = __builtin_amdgcn_mfma_f32_16x16x32_bf16(bfr[nt], af[mt][ks],
                                                                             acc[mt][nt], 0, 0, 0);
            }
            const int h = cg >> 2, r = cg & 3;
            const int colbase = (r * 4 + h) * 64;   // proj (n,r,h,f) layout
            const int cell = r * 4 + h;             // s_src/s_trg (n,r,h) layout
            const int scell = h * 4 + r;            // score-weight cell in wf (h,r)
            floatx4 sa4[4], sb4[4];
#pragma unroll
            for (int nt = 0; nt < 4; nt++) {
                sa4[nt] = *(const floatx4*)(wf + WF_SSC + scell * 64 + nt * 16 + q * 4);
                sb4[nt] = *(const floatx4*)(wf + WF_STC + scell * 64 + nt * 16 + q * 4);
            }
#pragma unroll
            for (int mt = 0; mt < 4; mt++) {
                const int row = m0 + mt * 16 + l15;
                float pa = 0.f, pb = 0.f;
#pragma unroll
                for (int nt = 0; nt < 4; nt++) {
                    short4v sv;
#pragma unroll
                    for (int rg = 0; rg < 4; rg++) {
                        float v = acc[mt][nt][rg];
                        unsigned short vb = (unsigned short)f2bf(v);
                        sv[rg] = (short)vb;
                        float vr = bf2f(vb);   // match prior bf16-rounded score path
                        pa = fmaf(vr, sa4[nt][rg], pa);
                        pb = fmaf(vr, sb4[nt][rg], pb);
                    }
                    if (row < NNODES)
                        *(short4v*)(proj + (size_t)row * 1024 + colbase + nt * 16 + q * 4) = sv;
                }
                pa += __shfl_xor(pa, 16);
                pa += __shfl_xor(pa, 32);
                pb += __shfl_xor(pb, 16);
                pb += __shfl_xor(pb, 32);
                if (q == 0 && row < NNODES) {
                    s_src[row * 16 + cell] = pa;
                    s_trg[row * 16 + cell] = pb;
                }
            }
        }
    } else {
#pragma unroll 1
        for (int cg = 0; cg < 4; cg++) {
            floatx4 acc[4][4];
#pragma unroll
            for (int i = 0; i < 4; i++)
#pragma unroll
                for (int j = 0; j < 4; j++) acc[i][j] = (floatx4){0.f, 0.f, 0.f, 0.f};
#pragma unroll
            for (int ks = 0; ks < 8; ks++) {
                short8 bfr[4];
#pragma unroll
                for (int nt = 0; nt < 4; nt++)
                    bfr[nt] = *(const short8*)(Bs + (size_t)(cg * 64 + nt * 16 + l15) * 256 + ks * 32 + q * 8);
#pragma unroll
                for (int mt = 0; mt < 4; mt++)
#pragma unroll
                    for (int nt = 0; nt < 4; nt++)
                        acc[mt][nt] = __builtin_amdgcn_mfma_f32_16x16x32_bf16(bfr[nt], af[mt][ks],
                                                                             acc[mt][nt], 0, 0, 0);
            }
#pragma unroll
            for (int mt = 0; mt < 4; mt++) {
                const int row = m0 + mt * 16 + l15;
                if (row >= NNODES) continue;
#pragma unroll
                for (int nt = 0; nt < 4; nt++) {
                    if (cf32) {
                        floatx4 o = acc[mt][nt];
                        *(floatx4*)(out32 + (size_t)row * 256 + cg * 64 + nt * 16 + q * 4) = o;
                    } else {
                        short4v sv;
#pragma unroll
                        for (int rg = 0; rg < 4; rg++)
                            sv[rg] = (short)f2bf(acc[mt][nt][rg]);
                        *(short4v*)(out16 + (size_t)row * 256 + cg * 64 + nt * 16 + q * 4) = sv;
                    }
                }
            }
        }
    }
}

// ---------------------------------------------------------------------------
// CSR build: count -> hierarchical scan -> fill
// ---------------------------------------------------------------------------
__global__ __launch_bounds__(256) void count_k(const int* __restrict__ trg,
                                               const int* __restrict__ rel,
                                               unsigned* __restrict__ counts, int E) {
    int e = blockIdx.x * 256 + threadIdx.x;
    if (e >= E) return;
    int g = clampi(trg[e], NNODES - 1);
    int r = clampi(rel[e], 3);
    atomicAdd(&counts[g * 4 + r], 1u);
}

__global__ __launch_bounds__(256) void scan1_k(const unsigned* __restrict__ counts,
                                               unsigned* __restrict__ offsets,
                                               unsigned* __restrict__ bsum) {
    __shared__ unsigned ts[256];
    int t = threadIdx.x;
    int base = blockIdx.x * 1024 + t * 4;
    uint4v c = {0u, 0u, 0u, 0u};
    if (base + 3 < NBINS) c = *(const uint4v*)(counts + base);
    else {
#pragma unroll
        for (int j = 0; j < 4; j++) c[j] = (base + j < NBINS) ? counts[base + j] : 0u;
    }
    ts[t] = c[0] + c[1] + c[2] + c[3];
    __syncthreads();
    for (int off = 1; off < 256; off <<= 1) {
        unsigned v = (t >= off) ? ts[t - off] : 0u;
        __syncthreads();
        ts[t] += v;
        __syncthreads();
    }
    unsigned pre = (t == 0) ? 0u : ts[t - 1];
    uint4v o;
    o[0] = pre;
    o[1] = pre + c[0];
    o[2] = pre + c[0] + c[1];
    o[3] = pre + c[0] + c[1] + c[2];
    if (base + 3 < NBINS) *(uint4v*)(offsets + base) = o;
    else {
#pragma unroll
        for (int j = 0; j < 4; j++) if (base + j < NBINS) offsets[base + j] = o[j];
    }
    if (t == 255) bsum[blockIdx.x] = ts[255];
}

__global__ __launch_bounds__(256) void scan2_k(unsigned* __restrict__ bsum,
                                               unsigned* __restrict__ offsets) {
    __shared__ unsigned ts[256];
    int t = threadIdx.x;
    unsigned v = (t < NSCANB) ? bsum[t] : 0u;
    ts[t] = v;
    __syncthreads();
    for (int off = 1; off < 256; off <<= 1) {
        unsigned u = (t >= off) ? ts[t - off] : 0u;
        __syncthreads();
        ts[t] += u;
        __syncthreads();
    }
    if (t < NSCANB) bsum[t] = (t == 0) ? 0u : ts[t - 1];
    if (t == 255) offsets[NBINS] = ts[255];
}

__global__ __launch_bounds__(256) void scan3_k(unsigned* __restrict__ offsets,
                                               unsigned* __restrict__ cursor,
                                               const unsigned* __restrict__ bsum) {
    int t = threadIdx.x;
    unsigned base = bsum[blockIdx.x];
    int idx = blockIdx.x * 1024 + t * 4;
    if (idx + 3 < NBINS) {
        uint4v o = *(const uint4v*)(offsets + idx);
        o[0] += base; o[1] += base; o[2] += base; o[3] += base;
        *(uint4v*)(offsets + idx) = o;
        *(uint4v*)(cursor + idx) = o;
    } else {
#pragma unroll
        for (int j = 0; j < 4; j++)
            if (idx + j < NBINS) {
                unsigned v = offsets[idx + j] + base;
                offsets[idx + j] = v;
                cursor[idx + j] = v;
            }
    }
}

__global__ __launch_bounds__(256) void fill_k(const int* __restrict__ src,
                                              const int* __restrict__ trg,
                                              const int* __restrict__ rel,
                                              const float* __restrict__ s_src,
                                              const float* __restrict__ s_trg,
                                              unsigned* __restrict__ cursor,
                                              unsigned* __restrict__ esrc,
                                              floatx4* __restrict__ eexp, int E) {
    int e = blockIdx.x * 256 + threadIdx.x;
    if (e >= E) return;
    int s = clampi(src[e], NNODES - 1);
    int g = clampi(trg[e], NNODES - 1);
    int r = clampi(rel[e], 3);
    unsigned pos = atomicAdd(&cursor[g * 4 + r], 1u);
    if (pos >= (unsigned)E) pos = E - 1;
    esrc[pos] = (unsigned)s;
    // s_src/s_trg layout (n, r, h): one floatx4 per gather
    floatx4 aa = *(const floatx4*)(s_src + s * 16 + r * 4);
    floatx4 bb = *(const floatx4*)(s_trg + g * 16 + r * 4);
    floatx4 v;
#pragma unroll
    for (int h = 0; h < 4; h++) {
        float val = aa[h] + bb[h];
        val = val > 0.f ? val : 0.2f * val;
        v[h] = expf(val);
    }
    eexp[pos] = v;
}

// ---------------------------------------------------------------------------
// node_fused_k: rowagg + MLP + final fused, one WAVE per node (4 nodes/wave
// serially, 4 waves/block). Eliminates the agg buffer (102MB write + 204MB
// read) and the sc round trip entirely; all staging in wave-private LDS
// (no barriers). Per node:
//   1) gather edges of bins n*4+r (CSR), accumulate att-weighted proj rows,
//      f2bf -> aggL[16 rows][72 bf16]  (16B-aligned rows, matches old agg
//      bf16 rounding)
//   2) MFMA MLP (identical math to old mlp_mfma_k) -> mish scores,
//      redistributed via shfl (lane h reads m[r][h] from lane r*16+h)
//   3) softmax over r, weighted sum from aggL, +skip+bias, ELU, LayerNorm
// ---------------------------------------------------------------------------
__device__ __forceinline__ void edge_acc(const unsigned* esrc, const floatx4* eexp,
                                         const unsigned short* proj, int r, int h,
                                         int lane, unsigned beg, unsigned end,
                                         float* a, float* den) {
    unsigned i = beg;
    for (; i + 2 <= end; i += 2) {
        unsigned s0 = esrc[i], s1 = esrc[i + 1];
        floatx4 pe0 = eexp[i], pe1 = eexp[i + 1];
        short4v v0 = *((const short4v*)(proj + (size_t)s0 * 1024 + r * 256) + lane);
        short4v v1 = *((const short4v*)(proj + (size_t)s1 * 1024 + r * 256) + lane);
        float p0 = pe0[h], p1 = pe1[h];
        *den += p0 + p1;
        a[0] = fmaf(p0, bf2f((unsigned short)v0[0]), a[0]);
        a[1] = fmaf(p0, bf2f((unsigned short)v0[1]), a[1]);
        a[2] = fmaf(p0, bf2f((unsigned short)v0[2]), a[2]);
        a[3] = fmaf(p0, bf2f((unsigned short)v0[3]), a[3]);
        a[0] = fmaf(p1, bf2f((unsigned short)v1[0]), a[0]);
        a[1] = fmaf(p1, bf2f((unsigned short)v1[1]), a[1]);
        a[2] = fmaf(p1, bf2f((unsigned short)v1[2]), a[2]);
        a[3] = fmaf(p1, bf2f((unsigned short)v1[3]), a[3]);
    }
    if (i < end) {
        unsigned s0 = esrc[i];
        floatx4 pe0 = eexp[i];
        short4v v0 = *((const short4v*)(proj + (size_t)s0 * 1024 + r * 256) + lane);
        float p0 = pe0[h];
        *den += p0;
        a[0] = fmaf(p0, bf2f((unsigned short)v0[0]), a[0]);
        a[1] = fmaf(p0, bf2f((unsigned short)v0[1]), a[1]);
        a[2] = fmaf(p0, bf2f((unsigned short)v0[2]), a[2]);
        a[3] = fmaf(p0, bf2f((unsigned short)v0[3]), a[3]);
    }
}

__global__ __launch_bounds__(256) void node_fused_k(const unsigned* __restrict__ offsets,
                                                    const unsigned* __restrict__ esrc,
                                                    const floatx4* __restrict__ eexp,
                                                    const unsigned short* __restrict__ proj,
                                                    const unsigned short* __restrict__ wbf16,
                                                    const float* __restrict__ wf,
                                                    const unsigned* __restrict__ flag,
                                                    unsigned short* __restrict__ out16,
                                                    float* __restrict__ out32) {
    __shared__ unsigned short aggL[4][16 * 72];  // bf16, row stride 72 (144B, 16B-mult)
    __shared__ float hidL[4][16 * 68];
    const bool f32 = (*flag != 0u);
    const int wave = threadIdx.x >> 6;
    const int lane = threadIdx.x & 63;
    const int l15 = lane & 15, q = lane >> 4;
    unsigned short* aL = aggL[wave];
    float* hL = hidL[wave];

    // MFMA weight fragments from pre-packed bf16 W1/W2 (row-major)
    short8 w1f[2][4], w2f[2][4];
#pragma unroll
    for (int ks = 0; ks < 2; ks++)
#pragma unroll
        for (int nt = 0; nt < 4; nt++) {
            w1f[ks][nt] = *(const short8*)(wbf16 + (nt * 16 + l15) * 64 + ks * 32 + q * 8);
            w2f[ks][nt] = *(const short8*)(wbf16 + 4096 + (nt * 16 + l15) * 64 + ks * 32 + q * 8);
        }
    float b1v[4], b2v[4], w3v[4];
#pragma unroll
    for (int nt = 0; nt < 4; nt++) {
        b1v[nt] = wf[WF_B1 + nt * 16 + l15];
        b2v[nt] = wf[WF_B2 + nt * 16 + l15];
        w3v[nt] = wf[WF_W3 + nt * 16 + l15];
    }
    const float b3v = wf[WF_B3];

    // final-phase per-lane constants: lane owns head q, cols c0..c0+3
    const int c0 = q * 64 + l15 * 4;
    const floatx4 bi = *(const floatx4*)(wf + WF_BIAS + c0);
    const floatx4 ga = *(const floatx4*)(wf + WF_GAMMA + c0);
    const floatx4 be = *(const floatx4*)(wf + WF_BETA + c0);

    const int wave_id = blockIdx.x * 4 + wave;
#pragma unroll 1
    for (int t = 0; t < 4; t++) {
        const int n = wave_id * 4 + t;   // 3125*4*4 = 50000 exactly

        // ---- 1) edge aggregation into aggL ----
#pragma unroll
        for (int r = 0; r < 4; r++) {
            const int bin = n * 4 + r;
            unsigned beg = offsets[bin], end = offsets[bin + 1];
            float a[4] = {0.f, 0.f, 0.f, 0.f};
            float den = 0.f;
            edge_acc(esrc, eexp, proj, r, q, lane, beg, end, a, &den);
            float inv = 1.f / (den + 1e-16f);
            short4v o;
            o[0] = (short)f2bf(a[0] * inv);
            o[1] = (short)f2bf(a[1] * inv);
            o[2] = (short)f2bf(a[2] * inv);
            o[3] = (short)f2bf(a[3] * inv);
            // row (r*4 + h) with h = q; cols l15*4..+3
            *(short4v*)(aL + (r * 4 + q) * 72 + l15 * 4) = o;
        }

        // ---- 2) MFMA MLP ----
        short8 a1[2];
#pragma unroll
        for (int ks = 0; ks < 2; ks++)
            a1[ks] = *(const short8*)(aL + l15 * 72 + ks * 32 + q * 8);
        floatx4 acc1[4];
#pragma unroll
        for (int nt = 0; nt < 4; nt++) {
            acc1[nt] = (floatx4){0.f, 0.f, 0.f, 0.f};
            acc1[nt] = __builtin_amdgcn_mfma_f32_16x16x32_bf16(a1[0], w1f[0][nt], acc1[nt], 0, 0, 0);
            acc1[nt] = __builtin_amdgcn_mfma_f32_16x16x32_bf16(a1[1], w1f[1][nt], acc1[nt], 0, 0, 0);
        }
#pragma unroll
        for (int nt = 0; nt < 4; nt++)
#pragma unroll
            for (int rg = 0; rg < 4; rg++)
                hL[(q * 4 + rg) * 68 + nt * 16 + l15] = fmaxf(acc1[nt][rg] + b1v[nt], 0.f);
        short8 a2[2];
#pragma unroll
        for (int ks = 0; ks < 2; ks++) {
            short8 rr;
#pragma unroll
            for (int j = 0; j < 8; j++)
                rr[j] = (short)f2bf(hL[l15 * 68 + ks * 32 + q * 8 + j]);
            a2[ks] = rr;
        }
        floatx4 acc2[4];
#pragma unroll
        for (int nt = 0; nt < 4; nt++) {
            acc2[nt] = (floatx4){0.f, 0.f, 0.f, 0.f};
            acc2[nt] = __builtin_amdgcn_mfma_f32_16x16x32_bf16(a2[0], w2f[0][nt], acc2[nt], 0, 0, 0);
            acc2[nt] = __builtin_amdgcn_mfma_f32_16x16x32_bf16(a2[1], w2f[1][nt], acc2[nt], 0, 0, 0);
        }
        float p[4];
#pragma unroll
        for (int rg = 0; rg < 4; rg++) {
            float s = 0.f;
#pragma unroll
            for (int nt = 0; nt < 4; nt++)
                s = fmaf(fmaxf(acc2[nt][rg] + b2v[nt], 0.f), w3v[nt], s);
            p[rg] = s;
        }
#pragma unroll
        for (int off = 1; off < 16; off <<= 1) {
#pragma unroll
            for (int rg = 0; rg < 4; rg++) p[rg] += __shfl_xor(p[rg], off);
        }
        // mish for (r = q, h = l15&3); static-index select (rule #20)
        float psel = (l15 & 2) ? ((l15 & 1) ? p[3] : p[2])
                               : ((l15 & 1) ? p[1] : p[0]);
        float acc = psel + b3v;
        float sp = fmaxf(acc, 0.f) + log1pf(expf(-fabsf(acc)));
        float msh = acc * tanhf(sp);

        // ---- 3) softmax over r + weighted sum + skip + ELU + LN ----
        // lane needs m[r][h=q] from lane (r*16 + q)
        float sv0 = __shfl(msh, 0 * 16 + q);
        float sv1 = __shfl(msh, 1 * 16 + q);
        float sv2 = __shfl(msh, 2 * 16 + q);
        float sv3 = __shfl(msh, 3 * 16 + q);
        float mx = fmaxf(fmaxf(sv0, sv1), fmaxf(sv2, sv3));
        float e0 = expf(sv0 - mx), e1 = expf(sv1 - mx);
        float e2 = expf(sv2 - mx), e3 = expf(sv3 - mx);
        float inv = 1.f / (e0 + e1 + e2 + e3);
        float er[4] = {e0 * inv, e1 * inv, e2 * inv, e3 * inv};

        float acc4[4] = {0.f, 0.f, 0.f, 0.f};
#pragma unroll
        for (int r = 0; r < 4; r++) {
            short4v av = *(const short4v*)(aL + (r * 4 + q) * 72 + l15 * 4);
            float e = er[r];
            acc4[0] = fmaf(e, bf2f((unsigned short)av[0]), acc4[0]);
            acc4[1] = fmaf(e, bf2f((unsigned short)av[1]), acc4[1]);
            acc4[2] = fmaf(e, bf2f((unsigned short)av[2]), acc4[2]);
            acc4[3] = fmaf(e, bf2f((unsigned short)av[3]), acc4[3]);
        }

        const size_t ob = (size_t)n * 256 + c0;
        float v[4];
        if (f32) {
            floatx4 sk = *(const floatx4*)(out32 + ob);
#pragma unroll
            for (int j = 0; j < 4; j++) v[j] = acc4[j] + sk[j] + bi[j];
        } else {
            short4v sk = *(const short4v*)(out16 + ob);
#pragma unroll
            for (int j = 0; j < 4; j++) v[j] = acc4[j] + bf2f((unsigned short)sk[j]) + bi[j];
        }
#pragma unroll
        for (int j = 0; j < 4; j++) v[j] = v[j] > 0.f ? v[j] : expm1f(v[j]);

        float s = v[0] + v[1] + v[2] + v[3];
        float qq = v[0] * v[0] + v[1] * v[1] + v[2] * v[2] + v[3] * v[3];
#pragma unroll
        for (int o = 1; o < 64; o <<= 1) {
            s += __shfl_xor(s, o);
            qq += __shfl_xor(qq, o);
        }
        float mu = s * (1.f / 256.f);
        float var = fmaxf(qq * (1.f / 256.f) - mu * mu, 0.f);
        float rstd = rsqrtf(var + 1e-5f);

        if (f32) {
            floatx4 o4;
#pragma unroll
            for (int j = 0; j < 4; j++) o4[j] = (v[j] - mu) * rstd * ga[j] + be[j];
            *(floatx4*)(out32 + ob) = o4;
        } else {
            short4v o4;
#pragma unroll
            for (int j = 0; j < 4; j++) o4[j] = (short)f2bf((v[j] - mu) * rstd * ga[j] + be[j]);
            *(short4v*)(out16 + ob) = o4;
        }
    }
}

// ---------------------------------------------------------------------------
// workspace layout (~226.86 MB). Overlays (serial-stream disjoint lifetimes):
//   xbf  -> former agg region (xbf read only by gemm_fused)
//   wpbf/wsbf -> eexp head (weights read by gemm_fused; eexp written by fill_k)
// agg/sc buffers eliminated by node_fused_k.
// ---------------------------------------------------------------------------
extern "C" void kernel_launch(void* const* d_in, const int* in_sizes, int n_in,
                              void* d_out, int out_size, void* d_ws, size_t ws_size,
                              hipStream_t stream) {
    if (ws_size < 226900000) return;

    const void* x      = d_in[0];
    const int* src     = (const int*)d_in[1];
    const int* trg     = (const int*)d_in[2];
    const int* rel     = (const int*)d_in[3];
    const void* W_proj = d_in[5];
    const void* ssc    = d_in[6];
    const void* stc    = d_in[7];
    const void* W1     = d_in[8];
    const void* b1     = d_in[9];
    const void* W2     = d_in[10];
    const void* b2     = d_in[11];
    const void* W3     = d_in[12];
    const void* b3     = d_in[13];
    const void* W_skip = d_in[14];
    const void* bias   = d_in[15];
    const void* gamma  = d_in[16];
    const void* beta   = d_in[17];
    unsigned short* out16 = (unsigned short*)d_out;
    float* out32          = (float*)d_out;

    char* w = (char*)d_ws;
    unsigned short* proj = (unsigned short*)(w + 0);
    unsigned short* xbf  = (unsigned short*)(w + 102400000);
    float* s_src         = (float*)(w + 204800000);
    float* s_trg         = (float*)(w + 208000000);
    floatx4* eexp        = (floatx4*)(w + 211200000);
    unsigned short* wpbf = (unsigned short*)(w + 211200000);  // overlay eexp head
    unsigned short* wsbf = (unsigned short*)(w + 212300000);  // overlay eexp head
    unsigned* esrc       = (unsigned*)(w + 219200000);
    unsigned* counts     = (unsigned*)(w + 221200000);
    unsigned* offsets    = (unsigned*)(w + 222000000);
    unsigned* cursor     = (unsigned*)(w + 222800016);
    float* wf            = (float*)(w + 226800016);          // 11204 floats = 44816 B
    unsigned short* wbf16= (unsigned short*)(w + 226844832); // 8192 shorts = 16384 B
    unsigned* flag       = (unsigned*)(w + 226861216);
    unsigned* bsum       = (unsigned*)(w + 226861224);       // 196*4 = 784 B

    hipMemsetAsync(counts, 0, NBINS * 4, stream);

    probe_k<<<1, 256, 0, stream>>>((const unsigned short*)x, flag);
    wconv_k<<<1, 1024, 0, stream>>>(W1, b1, W2, b2, W3, b3, ssc, stc, bias, gamma, beta,
                                    flag, wf, wbf16);
    convbf_k<<<(MPAD * 256) / (8 * 256), 256, 0, stream>>>(x, xbf, NNODES * 256,
                                                           MPAD * 256, flag);
    convbf_k<<<128, 256, 0, stream>>>(W_proj, wpbf, 1024 * 256, 1024 * 256, flag);
    convbf_k<<<32, 256, 0, stream>>>(W_skip, wsbf, 256 * 256, 256 * 256, flag);
    // proj + skip + score dots, one pass over A; cg-split across gridDim.y
    gemm_fused_k<<<dim3(784, 5), 64, 0, stream>>>(xbf, wpbf, wsbf, proj, out16, out32,
                                                  wf, s_src, s_trg, flag);
    count_k<<<1954, 256, 0, stream>>>(trg, rel, counts, NEDGES);
    scan1_k<<<NSCANB, 256, 0, stream>>>(counts, offsets, bsum);
    scan2_k<<<1, 256, 0, stream>>>(bsum, offsets);
    scan3_k<<<NSCANB, 256, 0, stream>>>(offsets, cursor, bsum);
    fill_k<<<1954, 256, 0, stream>>>(src, trg, rel, s_src, s_trg, cursor, esrc, eexp, NEDGES);
    // aggregation + MLP + softmax/skip/LN fused: one wave per node
    node_fused_k<<<3125, 256, 0, stream>>>(offsets, esrc, eexp, proj, wbf16, wf, flag,
                                           out16, out32);
}